// Round 1
// baseline (12.126 us; speedup 1.0000x reference)
//
#include <hip/hip_runtime.h>

#define H 1024
#define W 1024
#define N_SRC 128

// Zero-fill the output image with vectorized stores.
__global__ void zero_out_kernel(float4* __restrict__ out, int n4) {
    int i = blockIdx.x * blockDim.x + threadIdx.x;
    int stride = gridDim.x * blockDim.x;
    for (; i < n4; i += stride) {
        out[i] = make_float4(0.f, 0.f, 0.f, 0.f);
    }
}

// Each thread handles one source: bilinear splat of exp(log_flux) into the
// 2x2 footprint. Reference pairs x_pos with the ROW index and y_pos with the
// COLUMN index:
//   out[h][w] += exp(lf[n]) * clip(1-|h - x_pos[n]|,0,1) * clip(1-|w - y_pos[n]|,0,1)
__global__ void splat_kernel(const float* __restrict__ log_flux,
                             const float* __restrict__ x_pos,
                             const float* __restrict__ y_pos,
                             float* __restrict__ out) {
    int n = blockIdx.x * blockDim.x + threadIdx.x;
    if (n >= N_SRC) return;

    float f  = __expf(log_flux[n]);
    float x0 = x_pos[n];   // row coordinate
    float y0 = y_pos[n];   // col coordinate

    int h0 = (int)floorf(x0);
    int w0 = (int)floorf(y0);
    float fx = x0 - (float)h0;   // weight(h0) = 1-fx, weight(h0+1) = fx
    float fy = y0 - (float)w0;   // weight(w0) = 1-fy, weight(w0+1) = fy

    #pragma unroll
    for (int dh = 0; dh < 2; ++dh) {
        int h = h0 + dh;
        if (h < 0 || h >= H) continue;
        float wh = dh ? fx : (1.0f - fx);
        #pragma unroll
        for (int dw = 0; dw < 2; ++dw) {
            int w = w0 + dw;
            if (w < 0 || w >= W) continue;
            float ww = dw ? fy : (1.0f - fy);
            float v = f * wh * ww;
            if (v != 0.0f) atomicAdd(&out[h * W + w], v);
        }
    }
}

extern "C" void kernel_launch(void* const* d_in, const int* in_sizes, int n_in,
                              void* d_out, int out_size, void* d_ws, size_t ws_size,
                              hipStream_t stream) {
    const float* log_flux = (const float*)d_in[0];
    const float* x_pos    = (const float*)d_in[1];
    const float* y_pos    = (const float*)d_in[2];
    float* out = (float*)d_out;

    int n4 = (H * W) / 4;  // 262144 float4s
    int block = 256;
    int grid = 2048;       // grid-stride over 262144 -> 128 iters/thread... use enough blocks
    // 262144 / 256 = 1024 blocks covers it exactly in one pass
    grid = (n4 + block - 1) / block;

    zero_out_kernel<<<grid, block, 0, stream>>>((float4*)out, n4);
    splat_kernel<<<1, N_SRC, 0, stream>>>(log_flux, x_pos, y_pos, out);
}